// Round 7
// baseline (270.881 us; speedup 1.0000x reference)
//
#include <hip/hip_runtime.h>
#include <math.h>

// SoftKConv, round 7.
// r6 post-mortem: latency-bound (1337 cyc/node, no pipe >46%) — two causes:
// (1) node not provably wave-uniform => idp[c]/twp[c] became 64 VECTOR global
// loads feeding dagg's serial fma chain; (2) 32 v_readlane epilogue = VALU->
// SGPR hazard stalls. r7 keeps r6's structure and fixes plumbing:
//   - readfirstlane(node) => true s_load of idx/tkw rows into SGPRs, once
//   - r broadcast via LDS (1 dup-write + 8 uniform float4 reads -> VGPR fma)
//   - epilogue fk reads as adjacent half2v pairs (fuse to ds_read2_b32)

typedef __attribute__((ext_vector_type(2)))  _Float16 half2v;
typedef __attribute__((ext_vector_type(4)))  _Float16 half4v;
typedef __attribute__((ext_vector_type(8)))  _Float16 half8;
typedef __attribute__((ext_vector_type(16))) float    f32x16;

#define NK   32
#define DIM  128
// LDS: half-offset(k,d) = ((d>>3)*33 + k)*8 + (d&7); 16*33*8 = 4224 halves.
#define FKT_SZ 4224

// ---------------- Kernel 0: WT[n][k] = (f16) W[k][n] -----------------------
__global__ __launch_bounds__(256) void prep(const float* __restrict__ W,
                                            _Float16* __restrict__ WT) {
    int t  = blockIdx.x * 256 + threadIdx.x;   // 0..16383
    int nn = t >> 7, k = t & 127;
    WT[t] = (_Float16)W[k * 128 + nn];
}

// ---------------- Kernel 1: h = feat @ W -> f16, MFMA ----------------------
__global__ __launch_bounds__(256) void gemm128(
    const float* __restrict__ A, const _Float16* __restrict__ WT,
    _Float16* __restrict__ Hq, int n)
{
    const int wave = threadIdx.x >> 6;
    const int lane = threadIdx.x & 63;
    const int l31  = lane & 31;
    const int hf   = lane >> 5;

    const int row  = blockIdx.x * 128 + wave * 32 + l31;
    const int rowc = row < n ? row : n - 1;

    f32x16 acc[4];
#pragma unroll
    for (int t = 0; t < 4; ++t)
#pragma unroll
        for (int i = 0; i < 16; ++i) acc[t][i] = 0.0f;

    const float* ap = A + (size_t)rowc * 128 + 8 * hf;
#pragma unroll
    for (int s = 0; s < 8; ++s) {
        float4 b0 = *reinterpret_cast<const float4*>(ap + 16 * s);
        float4 b1 = *reinterpret_cast<const float4*>(ap + 16 * s + 4);
        half8 bf;
        bf[0] = (_Float16)b0.x; bf[1] = (_Float16)b0.y;
        bf[2] = (_Float16)b0.z; bf[3] = (_Float16)b0.w;
        bf[4] = (_Float16)b1.x; bf[5] = (_Float16)b1.y;
        bf[6] = (_Float16)b1.z; bf[7] = (_Float16)b1.w;
#pragma unroll
        for (int t = 0; t < 4; ++t) {
            half8 af = *reinterpret_cast<const half8*>(
                WT + (size_t)(l31 + 32 * t) * 128 + 16 * s + 8 * hf);
            acc[t] = __builtin_amdgcn_mfma_f32_32x32x16_f16(af, bf, acc[t], 0, 0, 0);
        }
    }

    if (row < n) {
        _Float16* hp = Hq + (size_t)row * 128;
#pragma unroll
        for (int t = 0; t < 4; ++t)
#pragma unroll
            for (int g = 0; g < 4; ++g) {
                half4v hv;
#pragma unroll
                for (int q = 0; q < 4; ++q) hv[q] = (_Float16)acc[t][4 * g + q];
                *reinterpret_cast<half4v*>(hp + 32 * t + 8 * g + 4 * hf) = hv;
            }
    }
}

// ---------------- Kernel 2: per-node soft medoid ---------------------------
// 128 threads = 2 waves = 2 independent nodes; per-wave LDS region, no
// barriers (LDS in-order within a wave).
__global__ __launch_bounds__(128, 4) void softk(
    const _Float16* __restrict__ hq, const float* __restrict__ bias,
    const float* __restrict__ tkw, const int* __restrict__ idx,
    float* __restrict__ out, int n)
{
    __shared__ __align__(16) _Float16 fkT[2][FKT_SZ];   // 16896 B
    __shared__ __align__(16) float    rbuf[2][NK];      //   256 B

    const int wave = threadIdx.x >> 6;
    const int lane = threadIdx.x & 63;
    int node = blockIdx.x * 2 + wave;
    if (node >= n) node = n - 1;            // duplicate compute; benign

    const int l31 = lane & 31;
    const int hf  = lane >> 5;

    // force wave-uniform base => scalar loads for whole idx/tkw rows
    const int node_u = __builtin_amdgcn_readfirstlane(node);
    const int*   idp = idx + (size_t)node_u * NK;
    const float* twp = tkw + (size_t)node_u * NK;

    // SGPR copies of the weight row (masked) — issued early, no vector loads
    float wreg[NK];
#pragma unroll
    for (int m = 0; m < NK; ++m) {
        int im = idp[m];                    // s_load
        wreg[m] = (im < 0) ? 0.0f : twp[m]; // s_load + s_cselect
    }

    // per-lane neighbor id / mask / weight for c = l31 (vector loads)
    const int vid = idx[(size_t)node * NK + l31];
    const int mkc = (vid < 0) ? 1 : 0;
    const int idr = mkc ? 0 : vid;
    const float wc = mkc ? 0.0f : tkw[(size_t)node * NK + l31];

    // ---- single gather: lane holds row l31, dims [16s + 8hf + j] ----
    const half8* bp = reinterpret_cast<const half8*>(hq + (size_t)idr * DIM);
    half8 frag[8];
#pragma unroll
    for (int s = 0; s < 8; ++s) frag[s] = bp[2 * s + hf];

    // ---- stage frags to LDS, fragment-order + 33-pad (writes at bank floor)
#pragma unroll
    for (int s = 0; s < 8; ++s) {
        int c = 2 * s + hf;
        *reinterpret_cast<half8*>(&fkT[wave][(c * 33 + l31) * 8]) = frag[s];
    }

    // gram = FK @ FK^T (f16 in, fp32 acc)
    f32x16 acc;
#pragma unroll
    for (int i = 0; i < 16; ++i) acc[i] = 0.0f;
#pragma unroll
    for (int s = 0; s < 8; ++s)
        acc = __builtin_amdgcn_mfma_f32_32x32x16_f16(frag[s], frag[s], acc, 0, 0, 0);

    // diagonal -> sq; C/D: col=l31, rowD=(reg&3)+8(reg>>2)+4hf
    float dval = acc[0];
#pragma unroll
    for (int reg = 0; reg < 16; ++reg) {
        int rD = (reg & 3) + 8 * (reg >> 2) + 4 * hf;
        if (rD == l31) dval = acc[reg];
    }
    const bool own = (((l31 >> 2) & 1) == hf);
    float oth = __shfl_xor(dval, 32, 64);
    float sq  = own ? dval : oth;           // sq[l31] in every lane

    // 9th MFMA: acc += -(sq_m + sq_c)/2  ->  acc = -d2/2 (hi/lo f16 split).
    {
        _Float16 shi = (_Float16)sq;
        _Float16 slo = (_Float16)(sq - (float)shi);
        _Float16 nh  = (_Float16)(-0.5f * (float)shi);
        _Float16 nl  = (_Float16)(-0.5f * (float)slo);
        _Float16 z   = (_Float16)0.0f, one = (_Float16)1.0f;
        half8 aext = {z, z, z, z, z, z, z, z};
        half8 bext = {z, z, z, z, z, z, z, z};
        if (hf == 0) {
            aext[0] = nh;  aext[1] = nl;  aext[2] = one; aext[3] = one;
            bext[0] = one; bext[1] = one; bext[2] = nh;  bext[3] = nl;
        }
        acc = __builtin_amdgcn_mfma_f32_32x32x16_f16(aext, bext, acc, 0, 0, 0);
    }

    // dagg[c=l31] = sum_m w[m]*dist[m][c]; w from SGPRs (cndmask by hf).
    // eps=1e-4 > homog-noise 3e-5: exact zero for diagonal/duplicates.
    float part = 0.0f;
#pragma unroll
    for (int reg = 0; reg < 16; ++reg) {
        const int c = (reg & 3) + 8 * (reg >> 2);
        float wr = hf ? wreg[c + 4] : wreg[c];           // rD = c + 4hf
        float d2 = fmaxf(-(acc[reg] + acc[reg]), 0.0f);
        float ds = (d2 > 1e-4f) ? __builtin_amdgcn_sqrtf(d2) : 0.0f;
        part = fmaf(wr, ds, part);
    }
    float sA = part + __shfl_xor(part, 32, 64);
    if (mkc || !(sA < 3.4028235e38f)) sA = 3.4028235e38f;

    // softmax over 32 k (duplicated across halves)
    float x  = -sA;
    float mx = x;
#pragma unroll
    for (int o = 16; o > 0; o >>= 1) mx = fmaxf(mx, __shfl_xor(mx, o, 32));
    float e  = __expf(x - mx);
    float se = e;
#pragma unroll
    for (int o = 16; o > 0; o >>= 1) se += __shfl_xor(se, o, 32);
    float r = e * __builtin_amdgcn_rcpf(se);
    r *= wc;
    float sr = r;
#pragma unroll
    for (int o = 16; o > 0; o >>= 1) sr += __shfl_xor(sr, o, 32);
    r = r * __builtin_amdgcn_rcpf(sr);
    if (mkc) r = 0.0f;                      // r_{k=l31} in every lane

    // broadcast r via LDS (dup-write same value from both halves; benign)
    rbuf[wave][l31] = r;

    // ---- epilogue: out[d] = sum_k r_k * fk[k][d]; 2 dims/lane ----
    // fk pairs at adjacent 16-B offsets (fuse to ds_read2_b32, 2-way banks =
    // free); r via wave-uniform float4 broadcast reads -> plain VGPR fma.
    const int d0 = 2 * lane;
    const _Float16* fb = &fkT[wave][((d0 >> 3) * 33) * 8 + (d0 & 7)];
    const float4* rb = reinterpret_cast<const float4*>(&rbuf[wave][0]);
    float o0 = 0.0f, o1 = 0.0f;
#pragma unroll
    for (int q = 0; q < 8; ++q) {
        float4 rv = rb[q];
        half2v h0 = *reinterpret_cast<const half2v*>(fb + 8 * (4 * q + 0));
        half2v h1 = *reinterpret_cast<const half2v*>(fb + 8 * (4 * q + 1));
        half2v h2 = *reinterpret_cast<const half2v*>(fb + 8 * (4 * q + 2));
        half2v h3 = *reinterpret_cast<const half2v*>(fb + 8 * (4 * q + 3));
        o0 = fmaf(rv.x, (float)h0[0], o0); o1 = fmaf(rv.x, (float)h0[1], o1);
        o0 = fmaf(rv.y, (float)h1[0], o0); o1 = fmaf(rv.y, (float)h1[1], o1);
        o0 = fmaf(rv.z, (float)h2[0], o0); o1 = fmaf(rv.z, (float)h2[1], o1);
        o0 = fmaf(rv.w, (float)h3[0], o0); o1 = fmaf(rv.w, (float)h3[1], o1);
    }
    float2 bv = *reinterpret_cast<const float2*>(bias + d0);
    float2 ov = { o0 + bv.x, o1 + bv.y };
    *reinterpret_cast<float2*>(out + (size_t)node * DIM + d0) = ov;
}

extern "C" void kernel_launch(void* const* d_in, const int* in_sizes, int n_in,
                              void* d_out, int out_size, void* d_ws, size_t ws_size,
                              hipStream_t stream) {
    const float* feat = (const float*)d_in[0];
    const float* W    = (const float*)d_in[1];
    const float* bias = (const float*)d_in[2];
    const float* tkw  = (const float*)d_in[3];
    const int*   idx  = (const int*)d_in[4];
    float* out = (float*)d_out;

    const int n = in_sizes[0] / DIM;                       // 50000
    _Float16* hq = (_Float16*)d_ws;                        // n*128*2 = 12.8 MB
    _Float16* wt = hq + (size_t)n * DIM;                   // 32 KB

    prep<<<64, 256, 0, stream>>>(W, wt);
    gemm128<<<(n + 127) / 128, 256, 0, stream>>>(feat, wt, hq, n);
    softk<<<(n + 1) / 2, 128, 0, stream>>>(hq, bias, tkw, idx, out, n);
}

// Round 8
// 162.031 us; speedup vs baseline: 1.6718x; 1.6718x over previous
//
#include <hip/hip_runtime.h>
#include <math.h>

// SoftKConv, round 8.
// r7 post-mortem: float wreg[32] spilled to scratch (WRITE_SIZE 25->425 MB =
// 128 B/thread) — the "scalar row load" scheme compiled to private-memory
// traffic. r8 reverts to the r4-PROVEN bpermute for w[rD] (16 shuffles) and
// keeps everything else that survived measurement:
//   - single 8 KB/node gather straight into MFMA fragments (r3)
//   - fragment-order LDS staging, 33-group pad (r6)
//   - homogeneous-coordinate 9th MFMA => acc = -d2/2, no sq broadcast (r5)
//   - rbuf LDS r-broadcast + ds_read2-fused VALU epilogue (r7)
// No arrays, no scalar gambles. Budget: ~430 LDS-cyc/node, ~210 VALU-cyc,
// 11 VMEM loads -> softk ~55-70 us.

typedef __attribute__((ext_vector_type(2)))  _Float16 half2v;
typedef __attribute__((ext_vector_type(4)))  _Float16 half4v;
typedef __attribute__((ext_vector_type(8)))  _Float16 half8;
typedef __attribute__((ext_vector_type(16))) float    f32x16;

#define NK   32
#define DIM  128
// LDS: half-offset(k,d) = ((d>>3)*33 + k)*8 + (d&7); 16*33*8 = 4224 halves.
#define FKT_SZ 4224

// ---------------- Kernel 0: WT[n][k] = (f16) W[k][n] -----------------------
__global__ __launch_bounds__(256) void prep(const float* __restrict__ W,
                                            _Float16* __restrict__ WT) {
    int t  = blockIdx.x * 256 + threadIdx.x;   // 0..16383
    int nn = t >> 7, k = t & 127;
    WT[t] = (_Float16)W[k * 128 + nn];
}

// ---------------- Kernel 1: h = feat @ W -> f16, MFMA ----------------------
__global__ __launch_bounds__(256) void gemm128(
    const float* __restrict__ A, const _Float16* __restrict__ WT,
    _Float16* __restrict__ Hq, int n)
{
    const int wave = threadIdx.x >> 6;
    const int lane = threadIdx.x & 63;
    const int l31  = lane & 31;
    const int hf   = lane >> 5;

    const int row  = blockIdx.x * 128 + wave * 32 + l31;
    const int rowc = row < n ? row : n - 1;

    f32x16 acc[4];
#pragma unroll
    for (int t = 0; t < 4; ++t)
#pragma unroll
        for (int i = 0; i < 16; ++i) acc[t][i] = 0.0f;

    const float* ap = A + (size_t)rowc * 128 + 8 * hf;
#pragma unroll
    for (int s = 0; s < 8; ++s) {
        float4 b0 = *reinterpret_cast<const float4*>(ap + 16 * s);
        float4 b1 = *reinterpret_cast<const float4*>(ap + 16 * s + 4);
        half8 bf;
        bf[0] = (_Float16)b0.x; bf[1] = (_Float16)b0.y;
        bf[2] = (_Float16)b0.z; bf[3] = (_Float16)b0.w;
        bf[4] = (_Float16)b1.x; bf[5] = (_Float16)b1.y;
        bf[6] = (_Float16)b1.z; bf[7] = (_Float16)b1.w;
#pragma unroll
        for (int t = 0; t < 4; ++t) {
            half8 af = *reinterpret_cast<const half8*>(
                WT + (size_t)(l31 + 32 * t) * 128 + 16 * s + 8 * hf);
            acc[t] = __builtin_amdgcn_mfma_f32_32x32x16_f16(af, bf, acc[t], 0, 0, 0);
        }
    }

    if (row < n) {
        _Float16* hp = Hq + (size_t)row * 128;
#pragma unroll
        for (int t = 0; t < 4; ++t)
#pragma unroll
            for (int g = 0; g < 4; ++g) {
                half4v hv;
#pragma unroll
                for (int q = 0; q < 4; ++q) hv[q] = (_Float16)acc[t][4 * g + q];
                *reinterpret_cast<half4v*>(hp + 32 * t + 8 * g + 4 * hf) = hv;
            }
    }
}

// ---------------- Kernel 2: per-node soft medoid ---------------------------
// 128 threads = 2 waves = 2 independent nodes; per-wave LDS region, no
// barriers (LDS in-order within a wave).
__global__ __launch_bounds__(128, 4) void softk(
    const _Float16* __restrict__ hq, const float* __restrict__ bias,
    const float* __restrict__ tkw, const int* __restrict__ idx,
    float* __restrict__ out, int n)
{
    __shared__ __align__(16) _Float16 fkT[2][FKT_SZ];   // 16896 B
    __shared__ __align__(16) float    rbuf[2][NK];      //   256 B

    const int wave = threadIdx.x >> 6;
    const int lane = threadIdx.x & 63;
    int node = blockIdx.x * 2 + wave;
    if (node >= n) node = n - 1;            // duplicate compute; benign

    const int l31 = lane & 31;
    const int hf  = lane >> 5;

    // per-lane neighbor id / mask / weight for c = l31 (plain vector loads)
    const int vid = idx[(size_t)node * NK + l31];
    const int mkc = (vid < 0) ? 1 : 0;
    const int idr = mkc ? 0 : vid;
    const float wc = mkc ? 0.0f : tkw[(size_t)node * NK + l31];

    // ---- single gather: lane holds row l31, dims [16s + 8hf + j] ----
    const half8* bp = reinterpret_cast<const half8*>(hq + (size_t)idr * DIM);
    half8 frag[8];
#pragma unroll
    for (int s = 0; s < 8; ++s) frag[s] = bp[2 * s + hf];

    // ---- stage frags to LDS, fragment-order + 33-pad (writes at bank floor)
#pragma unroll
    for (int s = 0; s < 8; ++s) {
        int c = 2 * s + hf;
        *reinterpret_cast<half8*>(&fkT[wave][(c * 33 + l31) * 8]) = frag[s];
    }

    // gram = FK @ FK^T (f16 in, fp32 acc)
    f32x16 acc;
#pragma unroll
    for (int i = 0; i < 16; ++i) acc[i] = 0.0f;
#pragma unroll
    for (int s = 0; s < 8; ++s)
        acc = __builtin_amdgcn_mfma_f32_32x32x16_f16(frag[s], frag[s], acc, 0, 0, 0);

    // diagonal -> sq; C/D: col=l31, rowD=(reg&3)+8(reg>>2)+4hf
    float dval = acc[0];
#pragma unroll
    for (int reg = 0; reg < 16; ++reg) {
        int rD = (reg & 3) + 8 * (reg >> 2) + 4 * hf;
        if (rD == l31) dval = acc[reg];
    }
    const bool own = (((l31 >> 2) & 1) == hf);
    float oth = __shfl_xor(dval, 32, 64);
    float sq  = own ? dval : oth;           // sq[l31] in every lane

    // 9th MFMA: acc += -(sq_m + sq_c)/2  ->  acc = -d2/2 (hi/lo f16 split).
    {
        _Float16 shi = (_Float16)sq;
        _Float16 slo = (_Float16)(sq - (float)shi);
        _Float16 nh  = (_Float16)(-0.5f * (float)shi);
        _Float16 nl  = (_Float16)(-0.5f * (float)slo);
        _Float16 z   = (_Float16)0.0f, one = (_Float16)1.0f;
        half8 aext = {z, z, z, z, z, z, z, z};
        half8 bext = {z, z, z, z, z, z, z, z};
        if (hf == 0) {
            aext[0] = nh;  aext[1] = nl;  aext[2] = one; aext[3] = one;
            bext[0] = one; bext[1] = one; bext[2] = nh;  bext[3] = nl;
        }
        acc = __builtin_amdgcn_mfma_f32_32x32x16_f16(aext, bext, acc, 0, 0, 0);
    }

    // dagg[c=l31] = sum_m w[m]*dist[m][c]; w[rD] via r4-proven bpermute.
    // eps=1e-4 > homog-noise 3e-5: exact zero for diagonal/duplicates.
    const int pbase = (lane & 32) + ((lane & 32) >> 3);   // hf=0 -> 0, hf=1 -> 36
    float part = 0.0f;
#pragma unroll
    for (int reg = 0; reg < 16; ++reg) {
        const int c = (reg & 3) + 8 * (reg >> 2);
        float wr = __shfl(wc, pbase + c, 64);            // w[c + 4hf]
        float d2 = fmaxf(-(acc[reg] + acc[reg]), 0.0f);
        float ds = (d2 > 1e-4f) ? __builtin_amdgcn_sqrtf(d2) : 0.0f;
        part = fmaf(wr, ds, part);
    }
    float sA = part + __shfl_xor(part, 32, 64);
    if (mkc || !(sA < 3.4028235e38f)) sA = 3.4028235e38f;

    // softmax over 32 k (duplicated across halves)
    float x  = -sA;
    float mx = x;
#pragma unroll
    for (int o = 16; o > 0; o >>= 1) mx = fmaxf(mx, __shfl_xor(mx, o, 32));
    float e  = __expf(x - mx);
    float se = e;
#pragma unroll
    for (int o = 16; o > 0; o >>= 1) se += __shfl_xor(se, o, 32);
    float r = e * __builtin_amdgcn_rcpf(se);
    r *= wc;
    float sr = r;
#pragma unroll
    for (int o = 16; o > 0; o >>= 1) sr += __shfl_xor(sr, o, 32);
    r = r * __builtin_amdgcn_rcpf(sr);
    if (mkc) r = 0.0f;                      // r_{k=l31} in every lane

    // broadcast r via LDS (dup-write same value from both halves; benign)
    rbuf[wave][l31] = r;

    // ---- epilogue: out[d] = sum_k r_k * fk[k][d]; 2 dims/lane ----
    // fk pairs at adjacent 16-B offsets (fuse to ds_read2_b32, 2-way banks =
    // free); r via wave-uniform float4 broadcast reads -> plain VGPR fma.
    const int d0 = 2 * lane;
    const _Float16* fb = &fkT[wave][((d0 >> 3) * 33) * 8 + (d0 & 7)];
    const float4* rb = reinterpret_cast<const float4*>(&rbuf[wave][0]);
    float o0 = 0.0f, o1 = 0.0f;
#pragma unroll
    for (int q = 0; q < 8; ++q) {
        float4 rv = rb[q];
        half2v h0 = *reinterpret_cast<const half2v*>(fb + 8 * (4 * q + 0));
        half2v h1 = *reinterpret_cast<const half2v*>(fb + 8 * (4 * q + 1));
        half2v h2 = *reinterpret_cast<const half2v*>(fb + 8 * (4 * q + 2));
        half2v h3 = *reinterpret_cast<const half2v*>(fb + 8 * (4 * q + 3));
        o0 = fmaf(rv.x, (float)h0[0], o0); o1 = fmaf(rv.x, (float)h0[1], o1);
        o0 = fmaf(rv.y, (float)h1[0], o0); o1 = fmaf(rv.y, (float)h1[1], o1);
        o0 = fmaf(rv.z, (float)h2[0], o0); o1 = fmaf(rv.z, (float)h2[1], o1);
        o0 = fmaf(rv.w, (float)h3[0], o0); o1 = fmaf(rv.w, (float)h3[1], o1);
    }
    float2 bv = *reinterpret_cast<const float2*>(bias + d0);
    float2 ov = { o0 + bv.x, o1 + bv.y };
    *reinterpret_cast<float2*>(out + (size_t)node * DIM + d0) = ov;
}

extern "C" void kernel_launch(void* const* d_in, const int* in_sizes, int n_in,
                              void* d_out, int out_size, void* d_ws, size_t ws_size,
                              hipStream_t stream) {
    const float* feat = (const float*)d_in[0];
    const float* W    = (const float*)d_in[1];
    const float* bias = (const float*)d_in[2];
    const float* tkw  = (const float*)d_in[3];
    const int*   idx  = (const int*)d_in[4];
    float* out = (float*)d_out;

    const int n = in_sizes[0] / DIM;                       // 50000
    _Float16* hq = (_Float16*)d_ws;                        // n*128*2 = 12.8 MB
    _Float16* wt = hq + (size_t)n * DIM;                   // 32 KB

    prep<<<64, 256, 0, stream>>>(W, wt);
    gemm128<<<(n + 127) / 128, 256, 0, stream>>>(feat, wt, hq, n);
    softk<<<(n + 1) / 2, 128, 0, stream>>>(hq, bias, tkw, idx, out, n);
}

// Round 9
// 155.625 us; speedup vs baseline: 1.7406x; 1.0412x over previous
//
#include <hip/hip_runtime.h>
#include <math.h>

// SoftKConv, round 9.
// r8 post-mortem: softk 68 us, latency-bound (836 cyc/node, VALU 47%, ~17
// dependent cross-lane ops ~500 cyc serial). r9 cuts the serial chain:
//   - algebraic softmax fusion: r = e*w / sum(e*w)  (se cancels; -5 shuffles,
//     -rcp, -mask select)
//   - sq via v_dot2_f32_f16 on frags, parallel to gram MFMAs (no diag
//     extract/exchange on the critical path; homog MFMA issues immediately)
//   - epilogue fk LDS reads hoisted above dagg/softmax (latency overlapped);
//     dagg 4-way tree accumulation
// Everything else r8-proven: single gather, fragment-order staging, homog
// 9th MFMA, bpermute w, rbuf broadcast, ds_read2 epilogue.

typedef __attribute__((ext_vector_type(2)))  _Float16 half2v;
typedef __attribute__((ext_vector_type(4)))  _Float16 half4v;
typedef __attribute__((ext_vector_type(8)))  _Float16 half8;
typedef __attribute__((ext_vector_type(16))) float    f32x16;

#define NK   32
#define DIM  128
// LDS: half-offset(k,d) = ((d>>3)*33 + k)*8 + (d&7); 16*33*8 = 4224 halves.
#define FKT_SZ 4224

// ---------------- Kernel 0: WT[n][k] = (f16) W[k][n] -----------------------
__global__ __launch_bounds__(256) void prep(const float* __restrict__ W,
                                            _Float16* __restrict__ WT) {
    int t  = blockIdx.x * 256 + threadIdx.x;   // 0..16383
    int nn = t >> 7, k = t & 127;
    WT[t] = (_Float16)W[k * 128 + nn];
}

// ---------------- Kernel 1: h = feat @ W -> f16, MFMA ----------------------
__global__ __launch_bounds__(256) void gemm128(
    const float* __restrict__ A, const _Float16* __restrict__ WT,
    _Float16* __restrict__ Hq, int n)
{
    const int wave = threadIdx.x >> 6;
    const int lane = threadIdx.x & 63;
    const int l31  = lane & 31;
    const int hf   = lane >> 5;

    const int row  = blockIdx.x * 128 + wave * 32 + l31;
    const int rowc = row < n ? row : n - 1;

    f32x16 acc[4];
#pragma unroll
    for (int t = 0; t < 4; ++t)
#pragma unroll
        for (int i = 0; i < 16; ++i) acc[t][i] = 0.0f;

    const float* ap = A + (size_t)rowc * 128 + 8 * hf;
#pragma unroll
    for (int s = 0; s < 8; ++s) {
        float4 b0 = *reinterpret_cast<const float4*>(ap + 16 * s);
        float4 b1 = *reinterpret_cast<const float4*>(ap + 16 * s + 4);
        half8 bf;
        bf[0] = (_Float16)b0.x; bf[1] = (_Float16)b0.y;
        bf[2] = (_Float16)b0.z; bf[3] = (_Float16)b0.w;
        bf[4] = (_Float16)b1.x; bf[5] = (_Float16)b1.y;
        bf[6] = (_Float16)b1.z; bf[7] = (_Float16)b1.w;
#pragma unroll
        for (int t = 0; t < 4; ++t) {
            half8 af = *reinterpret_cast<const half8*>(
                WT + (size_t)(l31 + 32 * t) * 128 + 16 * s + 8 * hf);
            acc[t] = __builtin_amdgcn_mfma_f32_32x32x16_f16(af, bf, acc[t], 0, 0, 0);
        }
    }

    if (row < n) {
        _Float16* hp = Hq + (size_t)row * 128;
#pragma unroll
        for (int t = 0; t < 4; ++t)
#pragma unroll
            for (int g = 0; g < 4; ++g) {
                half4v hv;
#pragma unroll
                for (int q = 0; q < 4; ++q) hv[q] = (_Float16)acc[t][4 * g + q];
                *reinterpret_cast<half4v*>(hp + 32 * t + 8 * g + 4 * hf) = hv;
            }
    }
}

// ---------------- Kernel 2: per-node soft medoid ---------------------------
// 128 threads = 2 waves = 2 independent nodes; per-wave LDS region, no
// barriers (LDS in-order within a wave).
__global__ __launch_bounds__(128, 4) void softk(
    const _Float16* __restrict__ hq, const float* __restrict__ bias,
    const float* __restrict__ tkw, const int* __restrict__ idx,
    float* __restrict__ out, int n)
{
    __shared__ __align__(16) _Float16 fkT[2][FKT_SZ];   // 16896 B
    __shared__ __align__(16) float    rbuf[2][NK];      //   256 B

    const int wave = threadIdx.x >> 6;
    const int lane = threadIdx.x & 63;
    int node = blockIdx.x * 2 + wave;
    if (node >= n) node = n - 1;            // duplicate compute; benign

    const int l31 = lane & 31;
    const int hf  = lane >> 5;

    // per-lane neighbor id / mask / weight for c = l31 (plain vector loads)
    const int vid = idx[(size_t)node * NK + l31];
    const int mkc = (vid < 0) ? 1 : 0;
    const int idr = mkc ? 0 : vid;
    const float wc = mkc ? 0.0f : tkw[(size_t)node * NK + l31];

    // bias for this lane's output dims (independent; issued early)
    const int d0 = 2 * lane;
    float2 bv = *reinterpret_cast<const float2*>(bias + d0);

    // ---- single gather: lane holds row l31, dims {16s + 8hf + j} ----
    const half8* bp = reinterpret_cast<const half8*>(hq + (size_t)idr * DIM);
    half8 frag[8];
#pragma unroll
    for (int s = 0; s < 8; ++s) frag[s] = bp[2 * s + hf];

    // ---- stage frags to LDS, fragment-order + 33-group pad ----
#pragma unroll
    for (int s = 0; s < 8; ++s) {
        int c = 2 * s + hf;
        *reinterpret_cast<half8*>(&fkT[wave][(c * 33 + l31) * 8]) = frag[s];
    }

    // gram = FK @ FK^T (f16 in, fp32 acc)
    f32x16 acc;
#pragma unroll
    for (int i = 0; i < 16; ++i) acc[i] = 0.0f;
#pragma unroll
    for (int s = 0; s < 8; ++s)
        acc = __builtin_amdgcn_mfma_f32_32x32x16_f16(frag[s], frag[s], acc, 0, 0, 0);

    // sq[l31] via fdot2 on frags — VALU path, overlaps the MFMAs above; no
    // dependency on acc (old diag-extract removed from the critical path).
    float sqp = 0.0f;
#pragma unroll
    for (int s = 0; s < 8; ++s) {
        const half2v* p2 = reinterpret_cast<const half2v*>(&frag[s]);
#pragma unroll
        for (int q = 0; q < 4; ++q)
            sqp = __builtin_amdgcn_fdot2(p2[q], p2[q], sqp, false);
    }
    float sq = sqp + __shfl_xor(sqp, 32, 64);   // full 128-dim |fk_l31|^2

    // 9th MFMA: acc += -(sq_m + sq_c)/2  ->  acc = -d2/2 (hi/lo f16 split).
    {
        _Float16 shi = (_Float16)sq;
        _Float16 slo = (_Float16)(sq - (float)shi);
        _Float16 nh  = (_Float16)(-0.5f * (float)shi);
        _Float16 nl  = (_Float16)(-0.5f * (float)slo);
        _Float16 z   = (_Float16)0.0f, one = (_Float16)1.0f;
        half8 aext = {z, z, z, z, z, z, z, z};
        half8 bext = {z, z, z, z, z, z, z, z};
        if (hf == 0) {
            aext[0] = nh;  aext[1] = nl;  aext[2] = one; aext[3] = one;
            bext[0] = one; bext[1] = one; bext[2] = nh;  bext[3] = nl;
        }
        acc = __builtin_amdgcn_mfma_f32_32x32x16_f16(aext, bext, acc, 0, 0, 0);
    }

    // ---- hoisted epilogue fk reads (depend only on staging writes) ----
    const _Float16* fb = &fkT[wave][((d0 >> 3) * 33) * 8 + (d0 & 7)];
    half2v ev[NK];
#pragma unroll
    for (int k = 0; k < NK; ++k)
        ev[k] = *reinterpret_cast<const half2v*>(fb + 8 * k);

    // dagg[c=l31] = sum_m w[m]*dist[m][c]; w[rD] via bpermute; 4-way tree.
    // eps=1e-4 > (homog + fdot2-diag) noise: exact zero for diag/duplicates.
    const int pbase = (lane & 32) + ((lane & 32) >> 3);   // hf=0 -> 0, hf=1 -> 36
    float pt[4] = {0.0f, 0.0f, 0.0f, 0.0f};
#pragma unroll
    for (int reg = 0; reg < 16; ++reg) {
        const int c = (reg & 3) + 8 * (reg >> 2);
        float wr = __shfl(wc, pbase + c, 64);            // w[c + 4hf]
        float d2 = fmaxf(-(acc[reg] + acc[reg]), 0.0f);
        float ds = (d2 > 1e-4f) ? __builtin_amdgcn_sqrtf(d2) : 0.0f;
        pt[reg & 3] = fmaf(wr, ds, pt[reg & 3]);
    }
    float part = (pt[0] + pt[1]) + (pt[2] + pt[3]);
    float sA = part + __shfl_xor(part, 32, 64);
    if (mkc || !(sA < 3.4028235e38f)) sA = 3.4028235e38f;

    // fused softmax + weight correction: r = e*w / sum(e*w)  (se cancels)
    float x  = -sA;
    float mx = x;
#pragma unroll
    for (int o = 16; o > 0; o >>= 1) mx = fmaxf(mx, __shfl_xor(mx, o, 32));
    float t  = __expf(x - mx) * wc;          // masked lanes: e->0 (and w=0)
    float st = t;
#pragma unroll
    for (int o = 16; o > 0; o >>= 1) st += __shfl_xor(st, o, 32);
    float r = t * __builtin_amdgcn_rcpf(st); // r_{k=l31} in every lane

    // broadcast r via LDS (dup-write same value from both halves; benign)
    rbuf[wave][l31] = r;

    // ---- epilogue: out[d] = sum_k r_k * fk[k][d]; fk already in ev[] ----
    const float4* rb = reinterpret_cast<const float4*>(&rbuf[wave][0]);
    float o0 = 0.0f, o1 = 0.0f;
#pragma unroll
    for (int q = 0; q < 8; ++q) {
        float4 rv = rb[q];
        o0 = fmaf(rv.x, (float)ev[4*q+0][0], o0); o1 = fmaf(rv.x, (float)ev[4*q+0][1], o1);
        o0 = fmaf(rv.y, (float)ev[4*q+1][0], o0); o1 = fmaf(rv.y, (float)ev[4*q+1][1], o1);
        o0 = fmaf(rv.z, (float)ev[4*q+2][0], o0); o1 = fmaf(rv.z, (float)ev[4*q+2][1], o1);
        o0 = fmaf(rv.w, (float)ev[4*q+3][0], o0); o1 = fmaf(rv.w, (float)ev[4*q+3][1], o1);
    }
    float2 ov = { o0 + bv.x, o1 + bv.y };
    *reinterpret_cast<float2*>(out + (size_t)node * DIM + d0) = ov;
}

extern "C" void kernel_launch(void* const* d_in, const int* in_sizes, int n_in,
                              void* d_out, int out_size, void* d_ws, size_t ws_size,
                              hipStream_t stream) {
    const float* feat = (const float*)d_in[0];
    const float* W    = (const float*)d_in[1];
    const float* bias = (const float*)d_in[2];
    const float* tkw  = (const float*)d_in[3];
    const int*   idx  = (const int*)d_in[4];
    float* out = (float*)d_out;

    const int n = in_sizes[0] / DIM;                       // 50000
    _Float16* hq = (_Float16*)d_ws;                        // n*128*2 = 12.8 MB
    _Float16* wt = hq + (size_t)n * DIM;                   // 32 KB

    prep<<<64, 256, 0, stream>>>(W, wt);
    gemm128<<<(n + 127) / 128, 256, 0, stream>>>(feat, wt, hq, n);
    softk<<<(n + 1) / 2, 128, 0, stream>>>(hq, bias, tkw, idx, out, n);
}